// Round 12
// baseline (314.490 us; speedup 1.0000x reference)
//
#include <hip/hip_runtime.h>
#include <hip/hip_bf16.h>
#include <stdint.h>

#define BB 2
#define TB 2048
#define DB 2048
#define HB 16
#define HDB 128
#define LB 64
#define MB 4096   // B*T

typedef __hip_bfloat16 bf16;
typedef __attribute__((ext_vector_type(8))) short bf16x8;
typedef __attribute__((ext_vector_type(4))) float f32x4;

#define MFMA_16x16x32 __builtin_amdgcn_mfma_f32_16x16x32_bf16

typedef __attribute__((address_space(3))) void lds_t;
typedef const __attribute__((address_space(1))) void gvm_t;

static __device__ __forceinline__ float bf2f(bf16 h) { return __bfloat162float(h); }
static __device__ __forceinline__ bf16 f2bf(float f) { return __float2bfloat16(f); }
union BV8 { bf16x8 v; bf16 e[8]; };

// chunk-granule XOR swizzle (16B chunks within a 128B row)
#define SWZC(r) (((r) ^ ((r) >> 3)) & 7)

// ================= merged prep kernel: block-range partitioned =============
// [0,4096): LN | [4096,8192): wconv wq | [8192,12288): wconv wk
// [12288,12544): fold_v | [12544,12800): fold_o | [12800,12804): biasv
// [12804,12836): biaso
__device__ void do_ln(const float* __restrict__ x, const float* __restrict__ g,
                      const float* __restrict__ be, bf16* __restrict__ xn,
                      int row, int tid, char* sm) {
  float* red = (float*)sm;
  const float4* xr = (const float4*)(x + (size_t)row * DB);
  float4 a = xr[2 * tid], b = xr[2 * tid + 1];
  float s = a.x + a.y + a.z + a.w + b.x + b.y + b.z + b.w;
  float s2 = a.x * a.x + a.y * a.y + a.z * a.z + a.w * a.w +
             b.x * b.x + b.y * b.y + b.z * b.z + b.w * b.w;
  for (int off = 32; off > 0; off >>= 1) {
    s += __shfl_down(s, off);
    s2 += __shfl_down(s2, off);
  }
  int w = tid >> 6, lane = tid & 63;
  if (lane == 0) { red[w] = s; red[4 + w] = s2; }
  __syncthreads();
  s = red[0] + red[1] + red[2] + red[3];
  s2 = red[4] + red[5] + red[6] + red[7];
  float mu = s * (1.f / DB);
  float var = s2 * (1.f / DB) - mu * mu;
  float rstd = rsqrtf(var + 1e-5f);
  const float4* gw = (const float4*)g;
  const float4* bb = (const float4*)be;
  float4 g0 = gw[2 * tid], g1 = gw[2 * tid + 1];
  float4 b0 = bb[2 * tid], b1 = bb[2 * tid + 1];
  BV8 u;
  u.e[0] = f2bf((a.x - mu) * rstd * g0.x + b0.x);
  u.e[1] = f2bf((a.y - mu) * rstd * g0.y + b0.y);
  u.e[2] = f2bf((a.z - mu) * rstd * g0.z + b0.z);
  u.e[3] = f2bf((a.w - mu) * rstd * g0.w + b0.w);
  u.e[4] = f2bf((b.x - mu) * rstd * g1.x + b1.x);
  u.e[5] = f2bf((b.y - mu) * rstd * g1.y + b1.y);
  u.e[6] = f2bf((b.z - mu) * rstd * g1.z + b1.z);
  u.e[7] = f2bf((b.w - mu) * rstd * g1.w + b1.w);
  *(bf16x8*)(xn + (size_t)row * DB + tid * 8) = u.v;
}

__device__ void do_wconv(const float* __restrict__ W, bf16* __restrict__ Wt,
                         int bx, int by, int tid, char* sm) {
  float(*t)[33] = (float(*)[33])sm;
  int c0 = bx * 32, r0 = by * 32;
  int tx = tid & 31, ty = tid >> 5;
  for (int p = 0; p < 4; ++p)
    t[ty + 8 * p][tx] = W[(size_t)(r0 + ty + 8 * p) * DB + c0 + tx];
  __syncthreads();
  for (int p = 0; p < 4; ++p)
    Wt[(size_t)(c0 + ty + 8 * p) * DB + r0 + tx] = f2bf(t[tx][ty + 8 * p]);
}

__device__ void do_fold_v(const float* __restrict__ wv, const float* __restrict__ wcv,
                          bf16* __restrict__ BtV, int bx, int h, int tid, char* sm) {
  float(*wvs)[36] = (float(*)[36])sm;
  int k0 = bx * 128;
  int l = tid & 63, ks = tid >> 6;
  float acc[32];
#pragma unroll
  for (int i = 0; i < 32; ++i) acc[i] = 0.f;
  for (int dc = 0; dc < 128; dc += 32) {
    __syncthreads();
    for (int i = tid; i < 128 * 32; i += 256) {
      int kk = i >> 5, dd = i & 31;
      wvs[kk][dd] = wv[(size_t)(k0 + kk) * DB + h * 128 + dc + dd];
    }
    __syncthreads();
    float wr[32];
#pragma unroll
    for (int dd = 0; dd < 32; ++dd) wr[dd] = wcv[(dc + dd) * 64 + l];
#pragma unroll
    for (int i = 0; i < 32; ++i) {
      const float4* row = (const float4*)&wvs[ks * 32 + i][0];
#pragma unroll
      for (int d4 = 0; d4 < 8; ++d4) {
        float4 w4 = row[d4];
        acc[i] += w4.x * wr[d4 * 4] + w4.y * wr[d4 * 4 + 1] +
                  w4.z * wr[d4 * 4 + 2] + w4.w * wr[d4 * 4 + 3];
      }
    }
  }
  bf16* dst = BtV + (size_t)(h * 64 + l) * DB + k0 + ks * 32;
#pragma unroll
  for (int i8 = 0; i8 < 4; ++i8) {
    BV8 u;
#pragma unroll
    for (int j = 0; j < 8; ++j) u.e[j] = f2bf(acc[i8 * 8 + j]);
    *(bf16x8*)(dst + i8 * 8) = u.v;
  }
}

__device__ void do_fold_o(const float* __restrict__ wo, const float* __restrict__ wd,
                          bf16* __restrict__ BtO, int bx, int h, int tid, char* sm) {
  float(*wos)[132] = (float(*)[132])sm;
  int n0 = bx * 128;
  int l = tid & 63, ns = tid >> 6;
  float acc[32];
#pragma unroll
  for (int i = 0; i < 32; ++i) acc[i] = 0.f;
  for (int dc = 0; dc < 128; dc += 32) {
    __syncthreads();
    for (int i = tid; i < 32 * 128; i += 256) {
      int dd = i >> 7, nn = i & 127;
      wos[dd][nn] = wo[(size_t)(h * 128 + dc + dd) * DB + n0 + nn];
    }
    __syncthreads();
    float wr[32];
#pragma unroll
    for (int d4 = 0; d4 < 8; ++d4) {
      float4 w4 = *(const float4*)&wd[l * 128 + dc + d4 * 4];
      wr[d4 * 4] = w4.x; wr[d4 * 4 + 1] = w4.y;
      wr[d4 * 4 + 2] = w4.z; wr[d4 * 4 + 3] = w4.w;
    }
#pragma unroll
    for (int dd = 0; dd < 32; ++dd) {
      float w = wr[dd];
      const float4* row = (const float4*)&wos[dd][ns * 32];
#pragma unroll
      for (int i4 = 0; i4 < 8; ++i4) {
        float4 a4 = row[i4];
        acc[i4 * 4 + 0] += a4.x * w; acc[i4 * 4 + 1] += a4.y * w;
        acc[i4 * 4 + 2] += a4.z * w; acc[i4 * 4 + 3] += a4.w * w;
      }
    }
  }
#pragma unroll
  for (int i = 0; i < 32; ++i)
    BtO[(size_t)(n0 + ns * 32 + i) * 1024 + h * 64 + l] = f2bf(acc[i]);
}

__global__ __launch_bounds__(256) void prep_kernel(
    const float* __restrict__ x, const float* __restrict__ ln_w,
    const float* __restrict__ ln_b, bf16* __restrict__ xn,
    const float* __restrict__ wq, const float* __restrict__ wk,
    bf16* __restrict__ wqkT,
    const float* __restrict__ wv, const float* __restrict__ wcv,
    bf16* __restrict__ BtV,
    const float* __restrict__ wo, const float* __restrict__ wd,
    bf16* __restrict__ BtO,
    const float* __restrict__ bv, const float* __restrict__ bcv,
    float* __restrict__ bvlat,
    const float* __restrict__ bd, const float* __restrict__ bo,
    float* __restrict__ bo2) {
  __shared__ __align__(16) char sm[18432];
  int b = blockIdx.x, tid = threadIdx.x;
  if (b < 4096) {
    do_ln(x, ln_w, ln_b, xn, b, tid, sm);
  } else if (b < 8192) {
    int bb = b - 4096;
    do_wconv(wq, wqkT, bb & 63, bb >> 6, tid, sm);
  } else if (b < 12288) {
    int bb = b - 8192;
    do_wconv(wk, wqkT + (size_t)2048 * 2048, bb & 63, bb >> 6, tid, sm);
  } else if (b < 12544) {
    int bb = b - 12288;
    do_fold_v(wv, wcv, BtV, bb & 15, bb >> 4, tid, sm);
  } else if (b < 12800) {
    int bb = b - 12544;
    do_fold_o(wo, wd, BtO, bb & 15, bb >> 4, tid, sm);
  } else if (b < 12804) {
    int j = (b - 12800) * 256 + tid;
    int h = j >> 6, l = j & 63;
    float s = bcv[l];
    for (int d = 0; d < 128; ++d) s += bv[h * 128 + d] * wcv[d * 64 + l];
    bvlat[j] = s;
  } else {
    float(*red)[64] = (float(*)[64])sm;
    int nl = tid & 63, ks = tid >> 6;
    int n = (b - 12804) * 64 + nl;
    float s = 0.f;
    for (int k = ks * 512; k < ks * 512 + 512; ++k)
      s += bd[k & 127] * wo[(size_t)k * DB + n];
    red[ks][nl] = s;
    __syncthreads();
    if (ks == 0) bo2[n] = bo[n] + red[0][nl] + red[1][nl] + red[2][nl] + red[3][nl];
  }
}

// ------- fused QKV GEMM + latent projection: N=5120=[q|k|vlat] ------------
// r5 main loop (BK=32, 2-barrier, global_load_lds w16). 1D grid 1280 with
// XCD-chunked mapping: XCD x owns m-tiles [4x,4x+4) x all 40 n-tiles, so
// each XCD's A-panel set (2 MB) is L2-resident. Epilogue as r8.
__global__ __launch_bounds__(256) void gemm_qkv_kernel(
    const bf16* __restrict__ A, const bf16* __restrict__ wqkT,
    const bf16* __restrict__ BtV,
    const float* __restrict__ bq, const float* __restrict__ bk,
    const float* __restrict__ bvl,
    const float* __restrict__ wcq, const float* __restrict__ wck,
    const float* __restrict__ bcq, const float* __restrict__ bck,
    bf16* __restrict__ qlat, bf16* __restrict__ klat, bf16* __restrict__ vlatT,
    const float* __restrict__ fcos, const float* __restrict__ fsin) {
  constexpr int K = DB;
  __shared__ __align__(16) char smem[49152];
  bf16* As = (bf16*)smem;                 // [128*32], dies after main loop
  bf16* Bs = (bf16*)(smem + 8192);        // [128*32], dies after main loop
  bf16* Qt = (bf16*)smem;                 // [128*128] overlays As/Bs post-loop
  bf16* Wt = (bf16*)(smem + 32768);       // [64*128] latent weight (bf16)
  int tid = threadIdx.x;
  int bid = blockIdx.x;
  int j = (bid & 7) * 160 + (bid >> 3);   // XCD-chunked linear index
  int mt = j / 40, nt = j - mt * 40;
  int m0 = mt * 128, n0 = nt * 128;
  int w = tid >> 6, l = tid & 63;
  int wr = w >> 1, wc = w & 1;
  int lrow = l & 15, lk = (l >> 4) * 8, ck = l >> 4;
  const bf16* Bsrc = (n0 < 4096) ? (wqkT + (size_t)n0 * K)
                                 : (BtV + (size_t)(n0 - 4096) * K);
  int sel = n0 >> 11;  // 0=q, 1=k, 2=vlat

  // load latent weight for q/k blocks (region disjoint from As/Bs)
  if (sel < 2) {
    const float* wcp = sel == 0 ? wcq : wck;
    for (int i = tid; i < 8192; i += 256) {
      int d = i >> 6, jj = i & 63;
      Wt[jj * 128 + (((d >> 3) ^ (jj & 7)) * 8) + (d & 7)] = f2bf(wcp[d * 64 + jj]);
    }
  }

  f32x4 zero4 = {0.f, 0.f, 0.f, 0.f};
  f32x4 acc[4][4];
  for (int m = 0; m < 4; ++m)
    for (int n = 0; n < 4; ++n) acc[m][n] = zero4;

  for (int kk = 0; kk < K / 32; ++kk) {
    int k0 = kk * 32;
    __syncthreads();
#pragma unroll
    for (int i = 0; i < 2; ++i) {
      int c = i * 256 + tid;
      int r = c >> 2, cc = c & 3;
      int cb = i * 256 + (tid & ~63);
      __builtin_amdgcn_global_load_lds(
          (gvm_t*)&A[(size_t)(m0 + r) * K + k0 + cc * 8], (lds_t*)&As[cb * 8], 16, 0, 0);
      __builtin_amdgcn_global_load_lds(
          (gvm_t*)&Bsrc[(size_t)r * K + k0 + cc * 8], (lds_t*)&Bs[cb * 8], 16, 0, 0);
    }
    __syncthreads();
    bf16x8 af[4], bfr[4];
    for (int m = 0; m < 4; ++m)
      af[m] = *(bf16x8*)&As[(wr * 64 + m * 16 + lrow) * 32 + lk];
    for (int n = 0; n < 4; ++n)
      bfr[n] = *(bf16x8*)&Bs[(wc * 64 + n * 16 + lrow) * 32 + lk];
    for (int m = 0; m < 4; ++m)
      for (int n = 0; n < 4; ++n)
        acc[m][n] = MFMA_16x16x32(af[m], bfr[n], acc[m][n], 0, 0, 0);
  }

  int rg = 4 * (l >> 4), cl = l & 15;
  if (sel == 2) {
    for (int mf = 0; mf < 4; ++mf) {
      int rowb = m0 + wr * 64 + mf * 16 + rg;
      for (int nf = 0; nf < 4; ++nf) {
        int col = n0 + wc * 64 + nf * 16 + cl;
        int colV = col - 4096;
        float bv_ = bvl[colV];
        size_t vbase = ((size_t)((rowb >> 11) * HB + (colV >> 6)) * 64 + (colV & 63)) * TB
                       + (rowb & (TB - 1));
        for (int r = 0; r < 4; ++r)
          vlatT[vbase + r] = f2bf(acc[mf][nf][r] + bv_);
      }
    }
    return;
  }

  // --- q/k epilogue: bias + RoPE -> Qt (swizzled), then latent proj -------
  const float* bias = sel == 0 ? bq : bk;
  __syncthreads();  // all As/Bs reads done before Qt overlay
  for (int mf = 0; mf < 4; ++mf) {
    int rowb = m0 + wr * 64 + mf * 16 + rg;
    int rl0 = wr * 64 + mf * 16 + rg;
    for (int nf = 0; nf < 4; ++nf) {
      int col = n0 + wc * 64 + nf * 16 + cl;
      int colL = col & 2047;
      int cloc = wc * 64 + nf * 16 + cl;
      float bv_ = bias[colL];
      for (int r = 0; r < 4; ++r) {
        int rr = rowb + r;
        float v = acc[mf][nf][r] + bv_;
        // RoPE: pairs adjacent cols; parity(col)==parity(lane)
        float pv = __shfl_xor(v, 1);
        int t = rr & (TB - 1);
        int pi = (col & 127) >> 1;
        float c = fcos[t * 64 + pi], sn = fsin[t * 64 + pi];
        v = (col & 1) ? (pv * sn + v * c) : (v * c - pv * sn);
        int rl = rl0 + r;
        Qt[rl * 128 + ((((cloc >> 3) ^ (rl & 7)) * 8) + (cloc & 7))] = f2bf(v);
      }
    }
  }
  __syncthreads();
  // proj: qlat(128x64) = Qt(128x128) @ Wt^T; wave w -> rows w*32..w*32+31
  f32x4 pacc[2][4];
#pragma unroll
  for (int mi = 0; mi < 2; ++mi)
#pragma unroll
    for (int nf = 0; nf < 4; ++nf) pacc[mi][nf] = zero4;
#pragma unroll
  for (int kc = 0; kc < 4; ++kc) {
    bf16x8 aq[2], bw[4];
#pragma unroll
    for (int mi = 0; mi < 2; ++mi) {
      int row = w * 32 + mi * 16 + lrow;
      aq[mi] = *(bf16x8*)&Qt[row * 128 + (((kc * 4 + ck) ^ (row & 7)) * 8)];
    }
#pragma unroll
    for (int nf = 0; nf < 4; ++nf) {
      int jrow = nf * 16 + lrow;
      bw[nf] = *(bf16x8*)&Wt[jrow * 128 + (((kc * 4 + ck) ^ (jrow & 7)) * 8)];
    }
#pragma unroll
    for (int mi = 0; mi < 2; ++mi)
#pragma unroll
      for (int nf = 0; nf < 4; ++nf)
        pacc[mi][nf] = MFMA_16x16x32(aq[mi], bw[nf], pacc[mi][nf], 0, 0, 0);
  }
  int head = (n0 & 2047) >> 7;
  const float* bias2 = sel == 0 ? bcq : bck;
  bf16* outp = sel == 0 ? qlat : klat;
#pragma unroll
  for (int mi = 0; mi < 2; ++mi)
#pragma unroll
    for (int nf = 0; nf < 4; ++nf) {
      int colj = nf * 16 + cl;
      float b2 = bias2[colj];
#pragma unroll
      for (int r = 0; r < 4; ++r) {
        int roG = m0 + w * 32 + mi * 16 + rg + r;
        outp[((size_t)roG * HB + head) * 64 + colj] = f2bf(pacc[mi][nf][r] + b2);
      }
    }
}

// ---------------- final GEMM: out(4096x2048 fp32) = aout(4096x1024)@BtO^T --
// 1D grid 512, XCD-chunked: XCD x owns m-tiles [4x,4x+4) x all 16 n-tiles.
__global__ __launch_bounds__(256) void gemm_out_kernel(
    const bf16* __restrict__ A, const bf16* __restrict__ Bt,
    const float* __restrict__ bias, float* __restrict__ Cout) {
  constexpr int K = 1024, N = DB;
  __shared__ __align__(16) bf16 As[128 * 32];
  __shared__ __align__(16) bf16 Bs[128 * 32];
  int tid = threadIdx.x;
  int bid = blockIdx.x;
  int j = (bid & 7) * 64 + (bid >> 3);
  int mt = j >> 4, nt = j & 15;
  int m0 = mt * 128, n0 = nt * 128;
  int w = tid >> 6, l = tid & 63;
  int wr = w >> 1, wc = w & 1;
  int lrow = l & 15, lk = (l >> 4) * 8;

  f32x4 zero4 = {0.f, 0.f, 0.f, 0.f};
  f32x4 acc[4][4];
  for (int m = 0; m < 4; ++m)
    for (int n = 0; n < 4; ++n) acc[m][n] = zero4;

  for (int kk = 0; kk < K / 32; ++kk) {
    int k0 = kk * 32;
    __syncthreads();
#pragma unroll
    for (int i = 0; i < 2; ++i) {
      int c = i * 256 + tid;
      int r = c >> 2, cc = c & 3;
      int cb = i * 256 + (tid & ~63);
      __builtin_amdgcn_global_load_lds(
          (gvm_t*)&A[(size_t)(m0 + r) * K + k0 + cc * 8], (lds_t*)&As[cb * 8], 16, 0, 0);
      __builtin_amdgcn_global_load_lds(
          (gvm_t*)&Bt[(size_t)(n0 + r) * K + k0 + cc * 8], (lds_t*)&Bs[cb * 8], 16, 0, 0);
    }
    __syncthreads();
    bf16x8 af[4], bfr[4];
    for (int m = 0; m < 4; ++m)
      af[m] = *(bf16x8*)&As[(wr * 64 + m * 16 + lrow) * 32 + lk];
    for (int n = 0; n < 4; ++n)
      bfr[n] = *(bf16x8*)&Bs[(wc * 64 + n * 16 + lrow) * 32 + lk];
    for (int m = 0; m < 4; ++m)
      for (int n = 0; n < 4; ++n)
        acc[m][n] = MFMA_16x16x32(af[m], bfr[n], acc[m][n], 0, 0, 0);
  }

  int rg = 4 * (l >> 4), cl = l & 15;
  for (int m = 0; m < 4; ++m) {
    int rowb = m0 + wr * 64 + m * 16 + rg;
    for (int n = 0; n < 4; ++n) {
      int col = n0 + wc * 64 + n * 16 + cl;
      float bv = bias[col];
      for (int r = 0; r < 4; ++r)
        Cout[(size_t)(rowb + r) * N + col] = acc[m][n][r] + bv;
    }
  }
}

// ----------------- causal flash attention over latents (L=64) -------------
// qlat/klat: (B,T,H,L); vlatT: (B,H,L,T); aout: (B,T,H,L).
// 512 blocks x 256 thr; block = q-tile pair {31-p, p} of 64 rows (4 waves).
// K/V double-buffered: issue tile t+1 loads before computing tile t; single
// vmcnt(0)+barrier per tile (2-phase counted pipeline).
__global__ __launch_bounds__(256) void attn_kernel(const bf16* __restrict__ qlat,
                                                   const bf16* __restrict__ klat,
                                                   const bf16* __restrict__ vlatT,
                                                   bf16* __restrict__ aout) {
  int tid = threadIdx.x, w = tid >> 6, l = tid & 63;
  int job = ((int)blockIdx.x & 7) * 64 + ((int)blockIdx.x >> 3);
  int bh = job >> 4, pair = job & 15;
  int h = bh & 15, b = bh >> 4;
  int lrow = l & 15, ck = l >> 4, hi4 = l >> 4;
  __shared__ __align__(16) bf16 Ks[2][64 * 64];
  __shared__ __align__(16) bf16 VsT[2][64 * 64];
  __shared__ __align__(16) bf16 Ps[4][16 * 64];
  f32x4 zero4 = {0.f, 0.f, 0.f, 0.f};

#define ASTAGE(buf, kv0)                                                          \
  {                                                                               \
    _Pragma("unroll") for (int i = 0; i < 2; ++i) {                               \
      int c = i * 256 + tid;                                                      \
      int row = c >> 3, ch = c & 7;                                               \
      int dst = (c & ~63) * 8;                                                    \
      __builtin_amdgcn_global_load_lds(                                           \
          (gvm_t*)(klat + ((size_t)(b * TB + (kv0) + row) * HB + h) * LB +        \
                   ((ch ^ SWZC(row)) * 8)),                                       \
          (lds_t*)&Ks[buf][dst], 16, 0, 0);                                       \
      __builtin_amdgcn_global_load_lds(                                           \
          (gvm_t*)(vlatT + ((size_t)bh * 64 + row) * TB + (kv0) +                 \
                   ((ch ^ SWZC(row)) * 8)),                                       \
          (lds_t*)&VsT[buf][dst], 16, 0, 0);                                      \
    }                                                                             \
  }

  for (int half = 0; half < 2; ++half) {
    int tile = half ? pair : 31 - pair;
    int q0 = tile * 64;
    const bf16* qp = qlat + ((size_t)(b * TB + q0 + w * 16 + lrow) * HB + h) * LB;
    bf16x8 qf0 = *(const bf16x8*)(qp + ck * 8);
    bf16x8 qf1 = *(const bf16x8*)(qp + 32 + ck * 8);
    float mr[4], lsum[4];
    f32x4 o[4];
    for (int r = 0; r < 4; ++r) { mr[r] = -1e30f; lsum[r] = 0.f; }
    for (int n = 0; n < 4; ++n) o[n] = zero4;

    // prologue: all prior readers done, then stage tile 0
    __syncthreads();
    ASTAGE(0, 0)
    asm volatile("s_waitcnt vmcnt(0)");
    __syncthreads();

    for (int kt = 0; kt <= tile; ++kt) {
      int cur = kt & 1;
      int kv0 = kt * 64;
      if (kt < tile) ASTAGE(cur ^ 1, kv0 + 64)
      // QK^T: S (16 q x 64 kv) per wave
      f32x4 s[4];
      __builtin_amdgcn_s_setprio(1);
#pragma unroll
      for (int kg = 0; kg < 4; ++kg) {
        int row = kg * 16 + lrow;
        int sw = SWZC(row);
        bf16x8 kf0 = *(bf16x8*)&Ks[cur][row * 64 + ((ck ^ sw) * 8)];
        bf16x8 kf1 = *(bf16x8*)&Ks[cur][row * 64 + (((ck + 4) ^ sw) * 8)];
        f32x4 a = zero4;
        a = MFMA_16x16x32(qf0, kf0, a, 0, 0, 0);
        a = MFMA_16x16x32(qf1, kf1, a, 0, 0, 0);
        s[kg] = a;
      }
      __builtin_amdgcn_s_setprio(0);
      // scale + mask (diag tile only; wave-uniform branch)
      float sc[4][4];
      bool diag = (kt == tile);
#pragma unroll
      for (int kg = 0; kg < 4; ++kg)
#pragma unroll
        for (int r = 0; r < 4; ++r) {
          float v = s[kg][r] * 0.125f;
          if (diag) {
            int kvg = kv0 + kg * 16 + lrow;
            int qr = q0 + w * 16 + 4 * hi4 + r;
            if (kvg > qr) v = -1e30f;
          }
          sc[kg][r] = v;
        }
      // online softmax
      float rm[4], f[4], psum[4];
#pragma unroll
      for (int r = 0; r < 4; ++r)
        rm[r] = fmaxf(fmaxf(sc[0][r], sc[1][r]), fmaxf(sc[2][r], sc[3][r]));
      for (int off = 8; off > 0; off >>= 1)
#pragma unroll
        for (int r = 0; r < 4; ++r) rm[r] = fmaxf(rm[r], __shfl_xor(rm[r], off));
#pragma unroll
      for (int r = 0; r < 4; ++r) {
        float mn = fmaxf(mr[r], rm[r]);
        f[r] = __expf(mr[r] - mn);
        mr[r] = mn;
      }
#pragma unroll
      for (int kg = 0; kg < 4; ++kg)
#pragma unroll
        for (int r = 0; r < 4; ++r) sc[kg][r] = __expf(sc[kg][r] - mr[r]);
#pragma unroll
      for (int r = 0; r < 4; ++r)
        psum[r] = sc[0][r] + sc[1][r] + sc[2][r] + sc[3][r];
      for (int off = 8; off > 0; off >>= 1)
#pragma unroll
        for (int r = 0; r < 4; ++r) psum[r] += __shfl_xor(psum[r], off);
#pragma unroll
      for (int r = 0; r < 4; ++r) lsum[r] = lsum[r] * f[r] + psum[r];
#pragma unroll
      for (int n = 0; n < 4; ++n) {
        f32x4 t = o[n];
        t[0] *= f[0]; t[1] *= f[1]; t[2] *= f[2]; t[3] *= f[3];
        o[n] = t;
      }
      // stage P (per-wave buffer; swizzled)
#pragma unroll
      for (int r = 0; r < 4; ++r) {
        int rq = 4 * hi4 + r;
        int sw8 = SWZC(rq) << 3;
#pragma unroll
        for (int kg = 0; kg < 4; ++kg)
          Ps[w][rq * 64 + ((kg * 16 + lrow) ^ sw8)] = f2bf(sc[kg][r]);
      }
      int swp = SWZC(lrow);
      bf16x8 pa0 = *(bf16x8*)&Ps[w][lrow * 64 + ((ck ^ swp) * 8)];
      bf16x8 pa1 = *(bf16x8*)&Ps[w][lrow * 64 + (((ck + 4) ^ swp) * 8)];
      // PV: o += P @ V
      __builtin_amdgcn_s_setprio(1);
#pragma unroll
      for (int n = 0; n < 4; ++n) {
        int row = n * 16 + lrow;
        int sw = SWZC(row);
        bf16x8 vf0 = *(bf16x8*)&VsT[cur][row * 64 + ((ck ^ sw) * 8)];
        bf16x8 vf1 = *(bf16x8*)&VsT[cur][row * 64 + (((ck + 4) ^ sw) * 8)];
        o[n] = MFMA_16x16x32(pa0, vf0, o[n], 0, 0, 0);
        o[n] = MFMA_16x16x32(pa1, vf1, o[n], 0, 0, 0);
      }
      __builtin_amdgcn_s_setprio(0);
      // publish tile kt+1 (and order: all reads of tile kt done block-wide)
      asm volatile("s_waitcnt vmcnt(0)");
      __syncthreads();
    }
    float inv[4];
#pragma unroll
    for (int r = 0; r < 4; ++r) inv[r] = 1.f / lsum[r];
#pragma unroll
    for (int n = 0; n < 4; ++n)
#pragma unroll
      for (int r = 0; r < 4; ++r) {
        size_t row = (size_t)b * TB + q0 + w * 16 + 4 * hi4 + r;
        aout[(row * HB + h) * LB + n * 16 + lrow] = f2bf(o[n][r] * inv[r]);
      }
  }
#undef ASTAGE
}

// --------------------------------------------------------------------------
extern "C" void kernel_launch(void* const* d_in, const int* in_sizes, int n_in,
                              void* d_out, int out_size, void* d_ws, size_t ws_size,
                              hipStream_t stream) {
  const float* x    = (const float*)d_in[0];
  const float* ln_w = (const float*)d_in[2];
  const float* ln_b = (const float*)d_in[3];
  const float* wq   = (const float*)d_in[4];
  const float* bq   = (const float*)d_in[5];
  const float* wk   = (const float*)d_in[6];
  const float* bk   = (const float*)d_in[7];
  const float* wv   = (const float*)d_in[8];
  const float* bv   = (const float*)d_in[9];
  const float* wo   = (const float*)d_in[10];
  const float* bo   = (const float*)d_in[11];
  const float* wcq  = (const float*)d_in[12];
  const float* bcq  = (const float*)d_in[13];
  const float* wck  = (const float*)d_in[14];
  const float* bck  = (const float*)d_in[15];
  const float* wcv  = (const float*)d_in[16];
  const float* bcv  = (const float*)d_in[17];
  const float* wd   = (const float*)d_in[18];
  const float* bd   = (const float*)d_in[19];
  const float* fcos = (const float*)d_in[20];
  const float* fsin = (const float*)d_in[21];

  char* ws = (char*)d_ws;
  bf16*  xn    = (bf16*)(ws);                 // 16.8 MB (A input; live thru gemm_qkv)
  bf16*  wqkT  = (bf16*)(ws + 16777216);      // 16.8 MB; dead after gemm -> aout
  bf16*  BtV   = (bf16*)(ws + 33554432);      //  4.2 MB (1024 x 2048)
  bf16*  BtO   = (bf16*)(ws + 37748736);      //  4.2 MB (2048 x 1024)
  bf16*  qlat  = (bf16*)(ws + 41943040);      //  8.4 MB (B,T,H,L)
  bf16*  klat  = (bf16*)(ws + 58720256);      //  8.4 MB (B,T,H,L)
  bf16*  vlatT = (bf16*)(ws + 75497472);      //  8.4 MB (B,H,L,T)
  float* bvlat = (float*)(ws + 83886080);     //  4 KB
  float* bo2   = (float*)(ws + 83890176);     //  8 KB
  bf16*  aoutp = wqkT;                        // reuse (weights dead after gemm)

  prep_kernel<<<12836, 256, 0, stream>>>(
      x, ln_w, ln_b, xn, wq, wk, wqkT, wv, wcv, BtV, wo, wd, BtO,
      bv, bcv, bvlat, bd, bo, bo2);

  gemm_qkv_kernel<<<1280, 256, 0, stream>>>(
      xn, wqkT, BtV, bq, bk, bvlat, wcq, wck, bcq, bck,
      qlat, klat, vlatT, fcos, fsin);

  attn_kernel<<<512, 256, 0, stream>>>(qlat, klat, vlatT, aoutp);

  gemm_out_kernel<<<512, 256, 0, stream>>>(aoutp, BtO, bo2, (float*)d_out);
}

// Round 14
// 283.196 us; speedup vs baseline: 1.1105x; 1.1105x over previous
//
#include <hip/hip_runtime.h>
#include <hip/hip_bf16.h>
#include <stdint.h>

#define BB 2
#define TB 2048
#define DB 2048
#define HB 16
#define HDB 128
#define LB 64
#define MB 4096   // B*T

typedef __hip_bfloat16 bf16;
typedef __attribute__((ext_vector_type(8))) short bf16x8;
typedef __attribute__((ext_vector_type(4))) float f32x4;

#define MFMA_16x16x32 __builtin_amdgcn_mfma_f32_16x16x32_bf16

typedef __attribute__((address_space(3))) void lds_t;
typedef const __attribute__((address_space(1))) void gvm_t;

static __device__ __forceinline__ float bf2f(bf16 h) { return __bfloat162float(h); }
static __device__ __forceinline__ bf16 f2bf(float f) { return __float2bfloat16(f); }
union BV8 { bf16x8 v; bf16 e[8]; };
union BV4 { ushort4 v; bf16 e[4]; };

// chunk-granule XOR swizzle (16B chunks within a 128B row)
#define SWZC(r) (((r) ^ ((r) >> 3)) & 7)

// ================= merged prep kernel: block-range partitioned =============
__device__ void do_ln(const float* __restrict__ x, const float* __restrict__ g,
                      const float* __restrict__ be, bf16* __restrict__ xn,
                      int row, int tid, char* sm) {
  float* red = (float*)sm;
  const float4* xr = (const float4*)(x + (size_t)row * DB);
  float4 a = xr[2 * tid], b = xr[2 * tid + 1];
  float s = a.x + a.y + a.z + a.w + b.x + b.y + b.z + b.w;
  float s2 = a.x * a.x + a.y * a.y + a.z * a.z + a.w * a.w +
             b.x * b.x + b.y * b.y + b.z * b.z + b.w * b.w;
  for (int off = 32; off > 0; off >>= 1) {
    s += __shfl_down(s, off);
    s2 += __shfl_down(s2, off);
  }
  int w = tid >> 6, lane = tid & 63;
  if (lane == 0) { red[w] = s; red[4 + w] = s2; }
  __syncthreads();
  s = red[0] + red[1] + red[2] + red[3];
  s2 = red[4] + red[5] + red[6] + red[7];
  float mu = s * (1.f / DB);
  float var = s2 * (1.f / DB) - mu * mu;
  float rstd = rsqrtf(var + 1e-5f);
  const float4* gw = (const float4*)g;
  const float4* bb = (const float4*)be;
  float4 g0 = gw[2 * tid], g1 = gw[2 * tid + 1];
  float4 b0 = bb[2 * tid], b1 = bb[2 * tid + 1];
  BV8 u;
  u.e[0] = f2bf((a.x - mu) * rstd * g0.x + b0.x);
  u.e[1] = f2bf((a.y - mu) * rstd * g0.y + b0.y);
  u.e[2] = f2bf((a.z - mu) * rstd * g0.z + b0.z);
  u.e[3] = f2bf((a.w - mu) * rstd * g0.w + b0.w);
  u.e[4] = f2bf((b.x - mu) * rstd * g1.x + b1.x);
  u.e[5] = f2bf((b.y - mu) * rstd * g1.y + b1.y);
  u.e[6] = f2bf((b.z - mu) * rstd * g1.z + b1.z);
  u.e[7] = f2bf((b.w - mu) * rstd * g1.w + b1.w);
  *(bf16x8*)(xn + (size_t)row * DB + tid * 8) = u.v;
}

__device__ void do_wconv(const float* __restrict__ W, bf16* __restrict__ Wt,
                         int bx, int by, int tid, char* sm) {
  float(*t)[33] = (float(*)[33])sm;
  int c0 = bx * 32, r0 = by * 32;
  int tx = tid & 31, ty = tid >> 5;
  for (int p = 0; p < 4; ++p)
    t[ty + 8 * p][tx] = W[(size_t)(r0 + ty + 8 * p) * DB + c0 + tx];
  __syncthreads();
  for (int p = 0; p < 4; ++p)
    Wt[(size_t)(c0 + ty + 8 * p) * DB + r0 + tx] = f2bf(t[tx][ty + 8 * p]);
}

__device__ void do_fold_v(const float* __restrict__ wv, const float* __restrict__ wcv,
                          bf16* __restrict__ BtV, int bx, int h, int tid, char* sm) {
  float(*wvs)[36] = (float(*)[36])sm;
  int k0 = bx * 128;
  int l = tid & 63, ks = tid >> 6;
  float acc[32];
#pragma unroll
  for (int i = 0; i < 32; ++i) acc[i] = 0.f;
  for (int dc = 0; dc < 128; dc += 32) {
    __syncthreads();
    for (int i = tid; i < 128 * 32; i += 256) {
      int kk = i >> 5, dd = i & 31;
      wvs[kk][dd] = wv[(size_t)(k0 + kk) * DB + h * 128 + dc + dd];
    }
    __syncthreads();
    float wr[32];
#pragma unroll
    for (int dd = 0; dd < 32; ++dd) wr[dd] = wcv[(dc + dd) * 64 + l];
#pragma unroll
    for (int i = 0; i < 32; ++i) {
      const float4* row = (const float4*)&wvs[ks * 32 + i][0];
#pragma unroll
      for (int d4 = 0; d4 < 8; ++d4) {
        float4 w4 = row[d4];
        acc[i] += w4.x * wr[d4 * 4] + w4.y * wr[d4 * 4 + 1] +
                  w4.z * wr[d4 * 4 + 2] + w4.w * wr[d4 * 4 + 3];
      }
    }
  }
  bf16* dst = BtV + (size_t)(h * 64 + l) * DB + k0 + ks * 32;
#pragma unroll
  for (int i8 = 0; i8 < 4; ++i8) {
    BV8 u;
#pragma unroll
    for (int j = 0; j < 8; ++j) u.e[j] = f2bf(acc[i8 * 8 + j]);
    *(bf16x8*)(dst + i8 * 8) = u.v;
  }
}

__device__ void do_fold_o(const float* __restrict__ wo, const float* __restrict__ wd,
                          bf16* __restrict__ BtO, int bx, int h, int tid, char* sm) {
  float(*wos)[132] = (float(*)[132])sm;
  int n0 = bx * 128;
  int l = tid & 63, ns = tid >> 6;
  float acc[32];
#pragma unroll
  for (int i = 0; i < 32; ++i) acc[i] = 0.f;
  for (int dc = 0; dc < 128; dc += 32) {
    __syncthreads();
    for (int i = tid; i < 32 * 128; i += 256) {
      int dd = i >> 7, nn = i & 127;
      wos[dd][nn] = wo[(size_t)(h * 128 + dc + dd) * DB + n0 + nn];
    }
    __syncthreads();
    float wr[32];
#pragma unroll
    for (int d4 = 0; d4 < 8; ++d4) {
      float4 w4 = *(const float4*)&wd[l * 128 + dc + d4 * 4];
      wr[d4 * 4] = w4.x; wr[d4 * 4 + 1] = w4.y;
      wr[d4 * 4 + 2] = w4.z; wr[d4 * 4 + 3] = w4.w;
    }
#pragma unroll
    for (int dd = 0; dd < 32; ++dd) {
      float w = wr[dd];
      const float4* row = (const float4*)&wos[dd][ns * 32];
#pragma unroll
      for (int i4 = 0; i4 < 8; ++i4) {
        float4 a4 = row[i4];
        acc[i4 * 4 + 0] += a4.x * w; acc[i4 * 4 + 1] += a4.y * w;
        acc[i4 * 4 + 2] += a4.z * w; acc[i4 * 4 + 3] += a4.w * w;
      }
    }
  }
#pragma unroll
  for (int i = 0; i < 32; ++i)
    BtO[(size_t)(n0 + ns * 32 + i) * 1024 + h * 64 + l] = f2bf(acc[i]);
}

__global__ __launch_bounds__(256) void prep_kernel(
    const float* __restrict__ x, const float* __restrict__ ln_w,
    const float* __restrict__ ln_b, bf16* __restrict__ xn,
    const float* __restrict__ wq, const float* __restrict__ wk,
    bf16* __restrict__ wqkT,
    const float* __restrict__ wv, const float* __restrict__ wcv,
    bf16* __restrict__ BtV,
    const float* __restrict__ wo, const float* __restrict__ wd,
    bf16* __restrict__ BtO,
    const float* __restrict__ bv, const float* __restrict__ bcv,
    float* __restrict__ bvlat,
    const float* __restrict__ bd, const float* __restrict__ bo,
    float* __restrict__ bo2) {
  __shared__ __align__(16) char sm[18432];
  int b = blockIdx.x, tid = threadIdx.x;
  if (b < 4096) {
    do_ln(x, ln_w, ln_b, xn, b, tid, sm);
  } else if (b < 8192) {
    int bb = b - 4096;
    do_wconv(wq, wqkT, bb & 63, bb >> 6, tid, sm);
  } else if (b < 12288) {
    int bb = b - 8192;
    do_wconv(wk, wqkT + (size_t)2048 * 2048, bb & 63, bb >> 6, tid, sm);
  } else if (b < 12544) {
    int bb = b - 12288;
    do_fold_v(wv, wcv, BtV, bb & 15, bb >> 4, tid, sm);
  } else if (b < 12800) {
    int bb = b - 12544;
    do_fold_o(wo, wd, BtO, bb & 15, bb >> 4, tid, sm);
  } else if (b < 12804) {
    int j = (b - 12800) * 256 + tid;
    int h = j >> 6, l = j & 63;
    float s = bcv[l];
    for (int d = 0; d < 128; ++d) s += bv[h * 128 + d] * wcv[d * 64 + l];
    bvlat[j] = s;
  } else {
    float(*red)[64] = (float(*)[64])sm;
    int nl = tid & 63, ks = tid >> 6;
    int n = (b - 12804) * 64 + nl;
    float s = 0.f;
    for (int k = ks * 512; k < ks * 512 + 512; ++k)
      s += bd[k & 127] * wo[(size_t)k * DB + n];
    red[ks][nl] = s;
    __syncthreads();
    if (ks == 0) bo2[n] = bo[n] + red[0][nl] + red[1][nl] + red[2][nl] + red[3][nl];
  }
}

// ------- fused QKV GEMM + latent projection: N=5120=[q|k|vlat] ------------
// r11 form (2D grid, BK=32, 2-barrier, global_load_lds w16, 48KB LDS).
__global__ __launch_bounds__(256) void gemm_qkv_kernel(
    const bf16* __restrict__ A, const bf16* __restrict__ wqkT,
    const bf16* __restrict__ BtV,
    const float* __restrict__ bq, const float* __restrict__ bk,
    const float* __restrict__ bvl,
    const float* __restrict__ wcq, const float* __restrict__ wck,
    const float* __restrict__ bcq, const float* __restrict__ bck,
    bf16* __restrict__ qlat, bf16* __restrict__ klat, bf16* __restrict__ vlatT,
    const float* __restrict__ fcos, const float* __restrict__ fsin) {
  constexpr int K = DB;
  __shared__ __align__(16) char smem[49152];
  bf16* As = (bf16*)smem;                 // [128*32], dies after main loop
  bf16* Bs = (bf16*)(smem + 8192);        // [128*32], dies after main loop
  bf16* Qt = (bf16*)smem;                 // [128*128] overlays As/Bs post-loop
  bf16* Wt = (bf16*)(smem + 32768);       // [64*128] latent weight (bf16)
  int tid = threadIdx.x;
  int m0 = blockIdx.y * 128, n0 = blockIdx.x * 128;
  int w = tid >> 6, l = tid & 63;
  int wr = w >> 1, wc = w & 1;
  int lrow = l & 15, lk = (l >> 4) * 8, ck = l >> 4;
  const bf16* Bsrc = (n0 < 4096) ? (wqkT + (size_t)n0 * K)
                                 : (BtV + (size_t)(n0 - 4096) * K);
  int sel = n0 >> 11;  // 0=q, 1=k, 2=vlat

  // load latent weight for q/k blocks (region disjoint from As/Bs)
  if (sel < 2) {
    const float* wcp = sel == 0 ? wcq : wck;
    for (int i = tid; i < 8192; i += 256) {
      int d = i >> 6, jj = i & 63;
      Wt[jj * 128 + (((d >> 3) ^ (jj & 7)) * 8) + (d & 7)] = f2bf(wcp[d * 64 + jj]);
    }
  }

  f32x4 zero4 = {0.f, 0.f, 0.f, 0.f};
  f32x4 acc[4][4];
  for (int m = 0; m < 4; ++m)
    for (int n = 0; n < 4; ++n) acc[m][n] = zero4;

  for (int kk = 0; kk < K / 32; ++kk) {
    int k0 = kk * 32;
    __syncthreads();
#pragma unroll
    for (int i = 0; i < 2; ++i) {
      int c = i * 256 + tid;
      int r = c >> 2, cc = c & 3;
      int cb = i * 256 + (tid & ~63);
      __builtin_amdgcn_global_load_lds(
          (gvm_t*)&A[(size_t)(m0 + r) * K + k0 + cc * 8], (lds_t*)&As[cb * 8], 16, 0, 0);
      __builtin_amdgcn_global_load_lds(
          (gvm_t*)&Bsrc[(size_t)r * K + k0 + cc * 8], (lds_t*)&Bs[cb * 8], 16, 0, 0);
    }
    __syncthreads();
    bf16x8 af[4], bfr[4];
    for (int m = 0; m < 4; ++m)
      af[m] = *(bf16x8*)&As[(wr * 64 + m * 16 + lrow) * 32 + lk];
    for (int n = 0; n < 4; ++n)
      bfr[n] = *(bf16x8*)&Bs[(wc * 64 + n * 16 + lrow) * 32 + lk];
    for (int m = 0; m < 4; ++m)
      for (int n = 0; n < 4; ++n)
        acc[m][n] = MFMA_16x16x32(af[m], bfr[n], acc[m][n], 0, 0, 0);
  }

  int rg = 4 * (l >> 4), cl = l & 15;
  if (sel == 2) {
    for (int mf = 0; mf < 4; ++mf) {
      int rowb = m0 + wr * 64 + mf * 16 + rg;
      for (int nf = 0; nf < 4; ++nf) {
        int col = n0 + wc * 64 + nf * 16 + cl;
        int colV = col - 4096;
        float bv_ = bvl[colV];
        size_t vbase = ((size_t)((rowb >> 11) * HB + (colV >> 6)) * 64 + (colV & 63)) * TB
                       + (rowb & (TB - 1));
        for (int r = 0; r < 4; ++r)
          vlatT[vbase + r] = f2bf(acc[mf][nf][r] + bv_);
      }
    }
    return;
  }

  // --- q/k epilogue: bias + RoPE -> Qt (swizzled), then latent proj -------
  const float* bias = sel == 0 ? bq : bk;
  __syncthreads();  // all As/Bs reads done before Qt overlay
  for (int mf = 0; mf < 4; ++mf) {
    int rowb = m0 + wr * 64 + mf * 16 + rg;
    int rl0 = wr * 64 + mf * 16 + rg;
    for (int nf = 0; nf < 4; ++nf) {
      int col = n0 + wc * 64 + nf * 16 + cl;
      int colL = col & 2047;
      int cloc = wc * 64 + nf * 16 + cl;
      float bv_ = bias[colL];
      for (int r = 0; r < 4; ++r) {
        int rr = rowb + r;
        float v = acc[mf][nf][r] + bv_;
        // RoPE: pairs adjacent cols; parity(col)==parity(lane)
        float pv = __shfl_xor(v, 1);
        int t = rr & (TB - 1);
        int pi = (col & 127) >> 1;
        float c = fcos[t * 64 + pi], sn = fsin[t * 64 + pi];
        v = (col & 1) ? (pv * sn + v * c) : (v * c - pv * sn);
        int rl = rl0 + r;
        Qt[rl * 128 + ((((cloc >> 3) ^ (rl & 7)) * 8) + (cloc & 7))] = f2bf(v);
      }
    }
  }
  __syncthreads();
  // proj: qlat(128x64) = Qt(128x128) @ Wt^T; wave w -> rows w*32..w*32+31
  f32x4 pacc[2][4];
#pragma unroll
  for (int mi = 0; mi < 2; ++mi)
#pragma unroll
    for (int nf = 0; nf < 4; ++nf) pacc[mi][nf] = zero4;
#pragma unroll
  for (int kc = 0; kc < 4; ++kc) {
    bf16x8 aq[2], bw[4];
#pragma unroll
    for (int mi = 0; mi < 2; ++mi) {
      int row = w * 32 + mi * 16 + lrow;
      aq[mi] = *(bf16x8*)&Qt[row * 128 + (((kc * 4 + ck) ^ (row & 7)) * 8)];
    }
#pragma unroll
    for (int nf = 0; nf < 4; ++nf) {
      int jrow = nf * 16 + lrow;
      bw[nf] = *(bf16x8*)&Wt[jrow * 128 + (((kc * 4 + ck) ^ (jrow & 7)) * 8)];
    }
#pragma unroll
    for (int mi = 0; mi < 2; ++mi)
#pragma unroll
      for (int nf = 0; nf < 4; ++nf)
        pacc[mi][nf] = MFMA_16x16x32(aq[mi], bw[nf], pacc[mi][nf], 0, 0, 0);
  }
  int head = (n0 & 2047) >> 7;
  const float* bias2 = sel == 0 ? bcq : bck;
  bf16* outp = sel == 0 ? qlat : klat;
#pragma unroll
  for (int mi = 0; mi < 2; ++mi)
#pragma unroll
    for (int nf = 0; nf < 4; ++nf) {
      int colj = nf * 16 + cl;
      float b2 = bias2[colj];
#pragma unroll
      for (int r = 0; r < 4; ++r) {
        int roG = m0 + w * 32 + mi * 16 + rg + r;
        outp[((size_t)roG * HB + head) * 64 + colj] = f2bf(pacc[mi][nf][r] + b2);
      }
    }
}

// ---------------- final GEMM: out(4096x2048 fp32) = aout(4096x1024)@BtO^T --
__global__ __launch_bounds__(256) void gemm_out_kernel(
    const bf16* __restrict__ A, const bf16* __restrict__ Bt,
    const float* __restrict__ bias, float* __restrict__ Cout) {
  constexpr int K = 1024, N = DB;
  __shared__ __align__(16) bf16 As[128 * 32];
  __shared__ __align__(16) bf16 Bs[128 * 32];
  int tid = threadIdx.x;
  int m0 = blockIdx.y * 128, n0 = blockIdx.x * 128;
  int w = tid >> 6, l = tid & 63;
  int wr = w >> 1, wc = w & 1;
  int lrow = l & 15, lk = (l >> 4) * 8;

  f32x4 zero4 = {0.f, 0.f, 0.f, 0.f};
  f32x4 acc[4][4];
  for (int m = 0; m < 4; ++m)
    for (int n = 0; n < 4; ++n) acc[m][n] = zero4;

  for (int kk = 0; kk < K / 32; ++kk) {
    int k0 = kk * 32;
    __syncthreads();
#pragma unroll
    for (int i = 0; i < 2; ++i) {
      int c = i * 256 + tid;
      int r = c >> 2, cc = c & 3;
      int cb = i * 256 + (tid & ~63);
      __builtin_amdgcn_global_load_lds(
          (gvm_t*)&A[(size_t)(m0 + r) * K + k0 + cc * 8], (lds_t*)&As[cb * 8], 16, 0, 0);
      __builtin_amdgcn_global_load_lds(
          (gvm_t*)&Bt[(size_t)(n0 + r) * K + k0 + cc * 8], (lds_t*)&Bs[cb * 8], 16, 0, 0);
    }
    __syncthreads();
    bf16x8 af[4], bfr[4];
    for (int m = 0; m < 4; ++m)
      af[m] = *(bf16x8*)&As[(wr * 64 + m * 16 + lrow) * 32 + lk];
    for (int n = 0; n < 4; ++n)
      bfr[n] = *(bf16x8*)&Bs[(wc * 64 + n * 16 + lrow) * 32 + lk];
    for (int m = 0; m < 4; ++m)
      for (int n = 0; n < 4; ++n)
        acc[m][n] = MFMA_16x16x32(af[m], bfr[n], acc[m][n], 0, 0, 0);
  }

  int rg = 4 * (l >> 4), cl = l & 15;
  for (int m = 0; m < 4; ++m) {
    int rowb = m0 + wr * 64 + m * 16 + rg;
    for (int n = 0; n < 4; ++n) {
      int col = n0 + wc * 64 + n * 16 + cl;
      float bv = bias[col];
      for (int r = 0; r < 4; ++r)
        Cout[(size_t)(rowb + r) * N + col] = acc[m][n][r] + bv;
    }
  }
}

// ----------------- causal flash attention over latents (L=64) -------------
// Swapped QK^T: s = mfma(K, Q) so each lane owns ONE q row (q = lane&15)
// with 16 kv values in regs -> in-lane softmax + 2 shfl_xor. Defer-max THR=8.
// K/V double-buffered, 2-phase counted staging. Ps packed 8B stores.
__global__ __launch_bounds__(256) void attn_kernel(const bf16* __restrict__ qlat,
                                                   const bf16* __restrict__ klat,
                                                   const bf16* __restrict__ vlatT,
                                                   bf16* __restrict__ aout) {
  int tid = threadIdx.x, w = tid >> 6, l = tid & 63;
  int job = ((int)blockIdx.x & 7) * 64 + ((int)blockIdx.x >> 3);
  int bh = job >> 4, pair = job & 15;
  int h = bh & 15, b = bh >> 4;
  int lrow = l & 15, ck = l >> 4, hi4 = l >> 4;
  __shared__ __align__(16) bf16 Ks[2][64 * 64];
  __shared__ __align__(16) bf16 VsT[2][64 * 64];
  __shared__ __align__(16) bf16 Ps[4][16 * 64];
  f32x4 zero4 = {0.f, 0.f, 0.f, 0.f};

#define ASTAGE(buf, kv0)                                                          \
  {                                                                               \
    _Pragma("unroll") for (int i = 0; i < 2; ++i) {                               \
      int c = i * 256 + tid;                                                      \
      int row = c >> 3, ch = c & 7;                                               \
      int dst = (c & ~63) * 8;                                                    \
      __builtin_amdgcn_global_load_lds(                                           \
          (gvm_t*)(klat + ((size_t)(b * TB + (kv0) + row) * HB + h) * LB +        \
                   ((ch ^ SWZC(row)) * 8)),                                       \
          (lds_t*)&Ks[buf][dst], 16, 0, 0);                                       \
      __builtin_amdgcn_global_load_lds(                                           \
          (gvm_t*)(vlatT + ((size_t)bh * 64 + row) * TB + (kv0) +                 \
                   ((ch ^ SWZC(row)) * 8)),                                       \
          (lds_t*)&VsT[buf][dst], 16, 0, 0);                                      \
    }                                                                             \
  }

  for (int half = 0; half < 2; ++half) {
    int tile = half ? pair : 31 - pair;
    int q0 = tile * 64;
    const bf16* qp = qlat + ((size_t)(b * TB + q0 + w * 16 + lrow) * HB + h) * LB;
    bf16x8 qf0 = *(const bf16x8*)(qp + ck * 8);
    bf16x8 qf1 = *(const bf16x8*)(qp + 32 + ck * 8);
    float mr = -1e30f, lsum = 0.f;
    f32x4 o[4];
    for (int n = 0; n < 4; ++n) o[n] = zero4;
    int qr = q0 + w * 16 + lrow;   // this lane's q row (softmax layout)
    int swq = SWZC(lrow);

    // prologue: all prior readers done, then stage tile 0
    __syncthreads();
    ASTAGE(0, 0)
    asm volatile("s_waitcnt vmcnt(0)");
    __syncthreads();

    for (int kt = 0; kt <= tile; ++kt) {
      int cur = kt & 1;
      int kv0 = kt * 64;
      if (kt < tile) ASTAGE(cur ^ 1, kv0 + 64)
      // QK^T swapped: s[kg] = K_kg^T-frag x Q-frag -> lane holds q=lane&15,
      // kv = kv0 + kg*16 + (lane>>4)*4 + r
      f32x4 s[4];
      __builtin_amdgcn_s_setprio(1);
#pragma unroll
      for (int kg = 0; kg < 4; ++kg) {
        int row = kg * 16 + lrow;
        int sw = SWZC(row);
        bf16x8 kf0 = *(bf16x8*)&Ks[cur][row * 64 + ((ck ^ sw) * 8)];
        bf16x8 kf1 = *(bf16x8*)&Ks[cur][row * 64 + (((ck + 4) ^ sw) * 8)];
        f32x4 a = zero4;
        a = MFMA_16x16x32(kf0, qf0, a, 0, 0, 0);
        a = MFMA_16x16x32(kf1, qf1, a, 0, 0, 0);
        s[kg] = a;
      }
      __builtin_amdgcn_s_setprio(0);
      // scale + mask
      float sc[4][4];
      bool diag = (kt == tile);
#pragma unroll
      for (int kg = 0; kg < 4; ++kg)
#pragma unroll
        for (int r = 0; r < 4; ++r) {
          float v = s[kg][r] * 0.125f;
          if (diag) {
            int kvg = kv0 + kg * 16 + hi4 * 4 + r;
            if (kvg > qr) v = -1e30f;
          }
          sc[kg][r] = v;
        }
      // row-max: in-lane over 16 + 2 cross-lane rounds (lanes sharing q)
      float rm = sc[0][0];
#pragma unroll
      for (int kg = 0; kg < 4; ++kg)
#pragma unroll
        for (int r = 0; r < 4; ++r) rm = fmaxf(rm, sc[kg][r]);
      rm = fmaxf(rm, __shfl_xor(rm, 16));
      rm = fmaxf(rm, __shfl_xor(rm, 32));
      // defer-max (THR=8): only rescale when some lane's max grew past slack
      bool resc = __any(rm > mr + 8.f);
      float f = 1.f;
      if (resc) {
        float mn = fmaxf(mr, rm);
        f = __expf(mr - mn);
        mr = mn;
      }
#pragma unroll
      for (int kg = 0; kg < 4; ++kg)
#pragma unroll
        for (int r = 0; r < 4; ++r) sc[kg][r] = __expf(sc[kg][r] - mr);
      float ps = 0.f;
#pragma unroll
      for (int kg = 0; kg < 4; ++kg)
#pragma unroll
        for (int r = 0; r < 4; ++r) ps += sc[kg][r];
      ps += __shfl_xor(ps, 16);
      ps += __shfl_xor(ps, 32);
      lsum = lsum * f + ps;
      if (resc) {
#pragma unroll
        for (int r = 0; r < 4; ++r) {
          float fo = __shfl(f, hi4 * 4 + r, 64);  // f lives at lane q (0..15)
#pragma unroll
          for (int n = 0; n < 4; ++n) o[n][r] *= fo;
        }
      }
      // store P (packed 8B per kg): Ps[q][kv], swizzled kv-chunks
#pragma unroll
      for (int kg = 0; kg < 4; ++kg) {
        BV4 p4;
#pragma unroll
        for (int r = 0; r < 4; ++r) p4.e[r] = f2bf(sc[kg][r]);
        int kvb = kg * 16 + hi4 * 4;
        *(ushort4*)&Ps[w][lrow * 64 + (((kvb >> 3) ^ swq) * 8) + (kvb & 7)] = p4.v;
      }
      bf16x8 pa0 = *(bf16x8*)&Ps[w][lrow * 64 + ((ck ^ swq) * 8)];
      bf16x8 pa1 = *(bf16x8*)&Ps[w][lrow * 64 + (((ck + 4) ^ swq) * 8)];
      // PV: o += P @ V
      __builtin_amdgcn_s_setprio(1);
#pragma unroll
      for (int n = 0; n < 4; ++n) {
        int row = n * 16 + lrow;
        int sw = SWZC(row);
        bf16x8 vf0 = *(bf16x8*)&VsT[cur][row * 64 + ((ck ^ sw) * 8)];
        bf16x8 vf1 = *(bf16x8*)&VsT[cur][row * 64 + (((ck + 4) ^ sw) * 8)];
        o[n] = MFMA_16x16x32(pa0, vf0, o[n], 0, 0, 0);
        o[n] = MFMA_16x16x32(pa1, vf1, o[n], 0, 0, 0);
      }
      __builtin_amdgcn_s_setprio(0);
      // publish tile kt+1 (and order: all reads of tile kt done block-wide)
      asm volatile("s_waitcnt vmcnt(0)");
      __syncthreads();
    }
    float inv[4];
#pragma unroll
    for (int r = 0; r < 4; ++r) {
      float lo = __shfl(lsum, hi4 * 4 + r, 64);
      inv[r] = 1.f / lo;
    }
#pragma unroll
    for (int n = 0; n < 4; ++n)
#pragma unroll
      for (int r = 0; r < 4; ++r) {
        size_t row = (size_t)b * TB + q0 + w * 16 + 4 * hi4 + r;
        aout[(row * HB + h) * LB + n * 16 + lrow] = f2bf(o[n][r] * inv[r]);
      }
  }
#undef ASTAGE
}

// --------------------------------------------------------------------------
extern "C" void kernel_launch(void* const* d_in, const int* in_sizes, int n_in,
                              void* d_out, int out_size, void* d_ws, size_t ws_size,
                              hipStream_t stream) {
  const float* x    = (const float*)d_in[0];
  const float* ln_w = (const float*)d_in[2];
  const float* ln_b = (const float*)d_in[3];
  const float* wq   = (const float*)d_in[4];
  const float* bq   = (const float*)d_in[5];
  const float* wk   = (const float*)d_in[6];
  const float* bk   = (const float*)d_in[7];
  const float* wv   = (const float*)d_in[8];
  const float* bv   = (const float*)d_in[9];
  const float* wo   = (const float*)d_in[10];
  const float* bo   = (const float*)d_in[11];
  const float* wcq  = (const float*)d_in[12];
  const float* bcq  = (const float*)d_in[13];
  const float* wck  = (const float*)d_in[14];
  const float* bck  = (const float*)d_in[15];
  const float* wcv  = (const float*)d_in[16];
  const float* bcv  = (const float*)d_in[17];
  const float* wd   = (const float*)d_in[18];
  const float* bd   = (const float*)d_in[19];
  const float* fcos = (const float*)d_in[20];
  const float* fsin = (const float*)d_in[21];

  char* ws = (char*)d_ws;
  bf16*  xn    = (bf16*)(ws);                 // 16.8 MB (A input; live thru gemm_qkv)
  bf16*  wqkT  = (bf16*)(ws + 16777216);      // 16.8 MB; dead after gemm -> aout
  bf16*  BtV   = (bf16*)(ws + 33554432);      //  4.2 MB (1024 x 2048)
  bf16*  BtO   = (bf16*)(ws + 37748736);      //  4.2 MB (2048 x 1024)
  bf16*  qlat  = (bf16*)(ws + 41943040);      //  8.4 MB (B,T,H,L)
  bf16*  klat  = (bf16*)(ws + 58720256);      //  8.4 MB (B,T,H,L)
  bf16*  vlatT = (bf16*)(ws + 75497472);      //  8.4 MB (B,H,L,T)
  float* bvlat = (float*)(ws + 83886080);     //  4 KB
  float* bo2   = (float*)(ws + 83890176);     //  8 KB
  bf16*  aoutp = wqkT;                        // reuse (weights dead after gemm)

  prep_kernel<<<12836, 256, 0, stream>>>(
      x, ln_w, ln_b, xn, wq, wk, wqkT, wv, wcv, BtV, wo, wd, BtO,
      bv, bcv, bvlat, bd, bo, bo2);

  gemm_qkv_kernel<<<dim3(40, 32), 256, 0, stream>>>(
      xn, wqkT, BtV, bq, bk, bvlat, wcq, wck, bcq, bck,
      qlat, klat, vlatT, fcos, fsin);

  attn_kernel<<<512, 256, 0, stream>>>(qlat, klat, vlatT, aoutp);

  gemm_out_kernel<<<dim3(16, 32), 256, 0, stream>>>(aoutp, BtO, bo2, (float*)d_out);
}